// Round 4
// baseline (650.552 us; speedup 1.0000x reference)
//
#include <hip/hip_runtime.h>
#include <hip/hip_bf16.h>

// LogicConv3d: B=64, C=32, H=32, W=32, K=64, P=28*28=784, S=16 gathers per side.
// Tree: 16 -> 8 -> 4 -> 2 -> 1 soft binary ops with softmax(w)·COEF coefficients.
//
// R4 design (lesson R2/R3: concurrent chunk-streams thrash per-XCD 4MiB L2):
//  - pack_offsets: int32 triples -> packed u16 flat offsets (3.2 MB ws).
//  - coef_kernel: softmax(w)·COEF -> float4 coefs (32 KB ws).
//  - main: grid 1024 = ALL-RESIDENT (4 blocks/CU @ launch_bounds(256,4)).
//    4 phase-locked image streams, x footprint ~1MB << 4MiB/XCD L2.
//    Double-buffered gathers (prefetch image i+1 during tree of image i).
//    Plain stores (R3's nontemporal store inflated WRITE 14x).

#define B_  64
#define C_  32
#define H_  32
#define W_  32
#define K_  64
#define P_  784
#define CHW (C_*H_*W_)      // 32768 floats
#define IMGB ((size_t)CHW * 4)   // 128 KB
#define HW  (H_*W_)         // 1024
#define SITES (K_*P_)       // 50176
#define BCHUNK 16

__constant__ float COEF_[16][4] = {
    {0, 0, 0, 0}, {0, 0, 0, 1}, {0, 1, 0, -1}, {0, 1, 0, 0},
    {0, 0, 1, -1}, {0, 0, 1, 0}, {0, 1, 1, -2}, {0, 1, 1, -1},
    {1, -1, -1, 1}, {1, -1, -1, 2}, {1, 0, -1, 0}, {1, 0, -1, 1},
    {1, -1, 0, 0}, {1, -1, 0, 1}, {1, 0, 0, -1}, {1, 0, 0, 0}
};

// ---- kernel 1: pack indices into u16 flat offsets (2 per u32) ----
__global__ __launch_bounds__(256) void pack_offsets(
    const int* __restrict__ a_idx, const int* __restrict__ b_idx,
    uint4* __restrict__ offs)   // [SITES][4] uint4 = 32 u16 offsets
{
    const int site = blockIdx.x * 256 + threadIdx.x;
    if (site >= SITES) return;

    unsigned int pk[16];
    {
        int tmp[48];
        const int4* v = (const int4*)(a_idx + (size_t)site * 48);
        #pragma unroll
        for (int j = 0; j < 12; ++j) ((int4*)tmp)[j] = v[j];
        #pragma unroll
        for (int l = 0; l < 8; ++l) {
            unsigned int o0 = (unsigned)(tmp[(2*l  )*3+2]*HW + tmp[(2*l  )*3+0]*W_ + tmp[(2*l  )*3+1]);
            unsigned int o1 = (unsigned)(tmp[(2*l+1)*3+2]*HW + tmp[(2*l+1)*3+0]*W_ + tmp[(2*l+1)*3+1]);
            pk[l] = o0 | (o1 << 16);
        }
    }
    {
        int tmp[48];
        const int4* v = (const int4*)(b_idx + (size_t)site * 48);
        #pragma unroll
        for (int j = 0; j < 12; ++j) ((int4*)tmp)[j] = v[j];
        #pragma unroll
        for (int l = 0; l < 8; ++l) {
            unsigned int o0 = (unsigned)(tmp[(2*l  )*3+2]*HW + tmp[(2*l  )*3+0]*W_ + tmp[(2*l  )*3+1]);
            unsigned int o1 = (unsigned)(tmp[(2*l+1)*3+2]*HW + tmp[(2*l+1)*3+0]*W_ + tmp[(2*l+1)*3+1]);
            pk[8 + l] = o0 | (o1 << 16);
        }
    }
    uint4* dst = offs + (size_t)site * 4;
    dst[0] = make_uint4(pk[0],  pk[1],  pk[2],  pk[3]);
    dst[1] = make_uint4(pk[4],  pk[5],  pk[6],  pk[7]);
    dst[2] = make_uint4(pk[8],  pk[9],  pk[10], pk[11]);
    dst[3] = make_uint4(pk[12], pk[13], pk[14], pk[15]);
}

// ---- kernel 2: softmax(w)·COEF -> float4 per (k, node) ----
__global__ __launch_bounds__(256) void coef_kernel(
    const float* __restrict__ w0, const float* __restrict__ w1,
    const float* __restrict__ w2, const float* __restrict__ w3,
    const float* __restrict__ w4,
    float4* __restrict__ cws)    // [K_*31]
{
    const int t = blockIdx.x * 256 + threadIdx.x;
    if (t >= K_ * 31) return;
    const int k = t / 31;
    const int node = t - k * 31;
    int d, l;
    if      (node < 16) { d = 0; l = node; }
    else if (node < 24) { d = 1; l = node - 16; }
    else if (node < 28) { d = 2; l = node - 24; }
    else if (node < 30) { d = 3; l = node - 28; }
    else                { d = 4; l = 0; }
    const float* W;
    switch (d) {
        case 0: W = w0; break;
        case 1: W = w1; break;
        case 2: W = w2; break;
        case 3: W = w3; break;
        default: W = w4; break;
    }
    const float* row = W + ((size_t)l * K_ + k) * 16;
    float m = row[0];
    #pragma unroll
    for (int o = 1; o < 16; ++o) m = fmaxf(m, row[o]);
    float e[16];
    float Z = 0.0f;
    #pragma unroll
    for (int o = 0; o < 16; ++o) { e[o] = expf(row[o] - m); Z += e[o]; }
    const float inv = 1.0f / Z;
    float c0 = 0.f, c1 = 0.f, c2 = 0.f, c3 = 0.f;
    #pragma unroll
    for (int o = 0; o < 16; ++o) {
        c0 += e[o] * COEF_[o][0];
        c1 += e[o] * COEF_[o][1];
        c2 += e[o] * COEF_[o][2];
        c3 += e[o] * COEF_[o][3];
    }
    cws[t] = make_float4(c0 * inv, c1 * inv, c2 * inv, c3 * inv);
}

// ---- kernel 3: main ----
__global__ __launch_bounds__(256, 4) void logicconv_main(
    const float* __restrict__ x,
    const uint4* __restrict__ offs,
    const float4* __restrict__ cws,
    float* __restrict__ out)
{
    __shared__ float4 sc[31];

    const int tid   = threadIdx.x;
    const int ptile = blockIdx.x;     // 0..3
    const int k     = blockIdx.y;     // 0..63
    const int grp   = blockIdx.z;     // 0..3 (slowest; all 1024 blocks resident)

    if (tid < 31) sc[tid] = cws[k * 31 + tid];
    __syncthreads();

    const int p = ptile * 256 + tid;
    if (p >= P_) return;   // no further barriers

    const int site = k * P_ + p;
    const uint4 q0 = offs[(size_t)site * 4 + 0];
    const uint4 q1 = offs[(size_t)site * 4 + 1];
    const uint4 q2 = offs[(size_t)site * 4 + 2];
    const uint4 q3 = offs[(size_t)site * 4 + 3];

    int offA[16], offB[16];   // BYTE offsets within one image
    {
        const unsigned int ua[8] = {q0.x, q0.y, q0.z, q0.w, q1.x, q1.y, q1.z, q1.w};
        const unsigned int ub[8] = {q2.x, q2.y, q2.z, q2.w, q3.x, q3.y, q3.z, q3.w};
        #pragma unroll
        for (int j = 0; j < 8; ++j) {
            offA[2*j    ] = (int)((ua[j] & 0xffffu) << 2);
            offA[2*j + 1] = (int)((ua[j] >> 16)     << 2);
            offB[2*j    ] = (int)((ub[j] & 0xffffu) << 2);
            offB[2*j + 1] = (int)((ub[j] >> 16)     << 2);
        }
    }

    const int b0 = grp * BCHUNK;
    const char* xb = (const char*)x + (size_t)b0 * IMGB;
    float* outp = out + (size_t)b0 * (K_ * P_) + (size_t)k * P_ + p;
    const size_t ostride = (size_t)K_ * P_;

    float cur[32], nxt[32];

    #define LOADALL(dst, base)                                        \
        _Pragma("unroll")                                             \
        for (int l = 0; l < 16; ++l) {                                \
            dst[l]      = *(const float*)((base) + offA[l]);          \
            dst[16 + l] = *(const float*)((base) + offB[l]);          \
        }

    #define TREE_STORE(v, img_i)                                                          \
        {                                                                                 \
            float y[16];                                                                  \
            _Pragma("unroll")                                                             \
            for (int l = 0; l < 16; ++l) {                                                \
                const float4 c = sc[l];                                                   \
                const float a = v[l], bb = v[16 + l];                                     \
                y[l] = fmaf(c.w, a * bb, fmaf(c.z, bb, fmaf(c.y, a, c.x)));               \
            }                                                                             \
            _Pragma("unroll")                                                             \
            for (int l = 0; l < 8; ++l) {                                                 \
                const float4 c = sc[16 + l];                                              \
                const float a = y[2*l], bb = y[2*l + 1];                                  \
                y[l] = fmaf(c.w, a * bb, fmaf(c.z, bb, fmaf(c.y, a, c.x)));               \
            }                                                                             \
            _Pragma("unroll")                                                             \
            for (int l = 0; l < 4; ++l) {                                                 \
                const float4 c = sc[24 + l];                                              \
                const float a = y[2*l], bb = y[2*l + 1];                                  \
                y[l] = fmaf(c.w, a * bb, fmaf(c.z, bb, fmaf(c.y, a, c.x)));               \
            }                                                                             \
            _Pragma("unroll")                                                             \
            for (int l = 0; l < 2; ++l) {                                                 \
                const float4 c = sc[28 + l];                                              \
                const float a = y[2*l], bb = y[2*l + 1];                                  \
                y[l] = fmaf(c.w, a * bb, fmaf(c.z, bb, fmaf(c.y, a, c.x)));               \
            }                                                                             \
            {                                                                             \
                const float4 c = sc[30];                                                  \
                const float a = y[0], bb = y[1];                                          \
                outp[(size_t)(img_i) * ostride] =                                         \
                    fmaf(c.w, a * bb, fmaf(c.z, bb, fmaf(c.y, a, c.x)));                  \
            }                                                                             \
        }

    LOADALL(cur, xb);                               // image 0
    for (int ii = 0; ii < BCHUNK / 2; ++ii) {
        const char* xb1 = xb + IMGB;                // image 2ii+1 (in-chunk)
        LOADALL(nxt, xb1);
        TREE_STORE(cur, 2 * ii);
        const char* xb2 = (ii < BCHUNK / 2 - 1) ? xb + 2 * IMGB : xb;  // clamp (last: dummy)
        LOADALL(cur, xb2);
        TREE_STORE(nxt, 2 * ii + 1);
        xb += 2 * IMGB;
    }

    #undef LOADALL
    #undef TREE_STORE
}

extern "C" void kernel_launch(void* const* d_in, const int* in_sizes, int n_in,
                              void* d_out, int out_size, void* d_ws, size_t ws_size,
                              hipStream_t stream) {
    const float* x     = (const float*)d_in[0];
    const float* w0    = (const float*)d_in[1];
    const float* w1    = (const float*)d_in[2];
    const float* w2    = (const float*)d_in[3];
    const float* w3    = (const float*)d_in[4];
    const float* w4    = (const float*)d_in[5];
    const int*   a_idx = (const int*)d_in[6];
    const int*   b_idx = (const int*)d_in[7];
    float* out = (float*)d_out;

    uint4*  offs = (uint4*)d_ws;                     // SITES*64 B = 3.2 MB
    float4* cws  = (float4*)((char*)d_ws + (size_t)SITES * 64);  // 64*31*16 B

    pack_offsets<<<(SITES + 255) / 256, 256, 0, stream>>>(a_idx, b_idx, offs);
    coef_kernel<<<(K_ * 31 + 255) / 256, 256, 0, stream>>>(w0, w1, w2, w3, w4, cws);

    dim3 grid(4, K_, B_ / BCHUNK);   // 1024 blocks = 4/CU, all resident
    logicconv_main<<<grid, 256, 0, stream>>>(x, offs, cws, out);
}

// Round 5
// 47.566 us; speedup vs baseline: 13.6767x; 13.6767x over previous
//
#include <hip/hip_runtime.h>
#include <hip/hip_bf16.h>

// LogicConv3d: B=64, C=32, H=32, W=32, K=64, P=28*28=784, S=16 gathers/side.
// R5: gather from LDS, not L2. R2-R4 showed scattered L2 gathers thrash the
// 4MiB/XCD L2 as soon as occupancy rises (FETCH 35MB -> 0.7-1.2GB). One image
// is 128KB = fits LDS. Block(1024) stages image b, then 8 groups of 128
// threads each own one k and gather from LDS (consecutive lanes = consecutive
// p = consecutive LDS elements -> conflict-free). Coefs via wave-uniform
// s_load (readfirstlane'd k). All global traffic is streaming/coalesced.

#define B_  64
#define C_  32
#define H_  32
#define W_  32
#define K_  64
#define P_  784
#define CHW (C_*H_*W_)      // 32768 floats = 128 KB
#define HW  (H_*W_)         // 1024
#define SITES (K_*P_)       // 50176
#define KPB 8               // k's per block
#define NKG (K_/KPB)        // 8 kgroups

__constant__ float COEF_[16][4] = {
    {0, 0, 0, 0}, {0, 0, 0, 1}, {0, 1, 0, -1}, {0, 1, 0, 0},
    {0, 0, 1, -1}, {0, 0, 1, 0}, {0, 1, 1, -2}, {0, 1, 1, -1},
    {1, -1, -1, 1}, {1, -1, -1, 2}, {1, 0, -1, 0}, {1, 0, -1, 1},
    {1, -1, 0, 0}, {1, -1, 0, 1}, {1, 0, 0, -1}, {1, 0, 0, 0}
};

// ---- kernel 1: pack indices into u16 flat offsets (2 per u32) ----
__global__ __launch_bounds__(256) void pack_offsets(
    const int* __restrict__ a_idx, const int* __restrict__ b_idx,
    uint4* __restrict__ offs)   // [SITES][4] uint4 = 32 u16 offsets
{
    const int site = blockIdx.x * 256 + threadIdx.x;
    if (site >= SITES) return;

    unsigned int pk[16];
    {
        int tmp[48];
        const int4* v = (const int4*)(a_idx + (size_t)site * 48);
        #pragma unroll
        for (int j = 0; j < 12; ++j) ((int4*)tmp)[j] = v[j];
        #pragma unroll
        for (int l = 0; l < 8; ++l) {
            unsigned int o0 = (unsigned)(tmp[(2*l  )*3+2]*HW + tmp[(2*l  )*3+0]*W_ + tmp[(2*l  )*3+1]);
            unsigned int o1 = (unsigned)(tmp[(2*l+1)*3+2]*HW + tmp[(2*l+1)*3+0]*W_ + tmp[(2*l+1)*3+1]);
            pk[l] = o0 | (o1 << 16);
        }
    }
    {
        int tmp[48];
        const int4* v = (const int4*)(b_idx + (size_t)site * 48);
        #pragma unroll
        for (int j = 0; j < 12; ++j) ((int4*)tmp)[j] = v[j];
        #pragma unroll
        for (int l = 0; l < 8; ++l) {
            unsigned int o0 = (unsigned)(tmp[(2*l  )*3+2]*HW + tmp[(2*l  )*3+0]*W_ + tmp[(2*l  )*3+1]);
            unsigned int o1 = (unsigned)(tmp[(2*l+1)*3+2]*HW + tmp[(2*l+1)*3+0]*W_ + tmp[(2*l+1)*3+1]);
            pk[8 + l] = o0 | (o1 << 16);
        }
    }
    uint4* dst = offs + (size_t)site * 4;
    dst[0] = make_uint4(pk[0],  pk[1],  pk[2],  pk[3]);
    dst[1] = make_uint4(pk[4],  pk[5],  pk[6],  pk[7]);
    dst[2] = make_uint4(pk[8],  pk[9],  pk[10], pk[11]);
    dst[3] = make_uint4(pk[12], pk[13], pk[14], pk[15]);
}

// ---- kernel 2: softmax(w)·COEF -> float4 per (k, node) ----
__global__ __launch_bounds__(256) void coef_kernel(
    const float* __restrict__ w0, const float* __restrict__ w1,
    const float* __restrict__ w2, const float* __restrict__ w3,
    const float* __restrict__ w4,
    float4* __restrict__ cws)    // [K_*31]
{
    const int t = blockIdx.x * 256 + threadIdx.x;
    if (t >= K_ * 31) return;
    const int k = t / 31;
    const int node = t - k * 31;
    int d, l;
    if      (node < 16) { d = 0; l = node; }
    else if (node < 24) { d = 1; l = node - 16; }
    else if (node < 28) { d = 2; l = node - 24; }
    else if (node < 30) { d = 3; l = node - 28; }
    else                { d = 4; l = 0; }
    const float* W;
    switch (d) {
        case 0: W = w0; break;
        case 1: W = w1; break;
        case 2: W = w2; break;
        case 3: W = w3; break;
        default: W = w4; break;
    }
    const float* row = W + ((size_t)l * K_ + k) * 16;
    float m = row[0];
    #pragma unroll
    for (int o = 1; o < 16; ++o) m = fmaxf(m, row[o]);
    float e[16];
    float Z = 0.0f;
    #pragma unroll
    for (int o = 0; o < 16; ++o) { e[o] = expf(row[o] - m); Z += e[o]; }
    const float inv = 1.0f / Z;
    float c0 = 0.f, c1 = 0.f, c2 = 0.f, c3 = 0.f;
    #pragma unroll
    for (int o = 0; o < 16; ++o) {
        c0 += e[o] * COEF_[o][0];
        c1 += e[o] * COEF_[o][1];
        c2 += e[o] * COEF_[o][2];
        c3 += e[o] * COEF_[o][3];
    }
    cws[t] = make_float4(c0 * inv, c1 * inv, c2 * inv, c3 * inv);
}

// ---- kernel 3: main (LDS-gather) ----
__global__ __launch_bounds__(1024) void logicconv_main(
    const float* __restrict__ x,
    const uint4* __restrict__ offs,
    const float4* __restrict__ cws,
    float* __restrict__ out)
{
    __shared__ float simg[CHW];   // 128 KB

    const int tid = threadIdx.x;
    const int bid = blockIdx.x;
    const int b   = bid >> 3;     // image (kg fastest: 8 blocks stage same image ~concurrently)
    const int kg  = bid & 7;

    // ---- stage image b into LDS (coalesced float4) ----
    {
        const float4* xi = (const float4*)(x + (size_t)b * CHW);
        float4* si = (float4*)simg;
        #pragma unroll
        for (int j = 0; j < CHW / 4 / 1024; ++j)   // 8 iters
            si[tid + j * 1024] = xi[tid + j * 1024];
    }
    __syncthreads();

    // ---- 8 groups of 128 threads; each group owns one k (wave-uniform) ----
    const int g    = __builtin_amdgcn_readfirstlane(tid >> 7);   // 0..7
    const int lane = tid & 127;
    const int k    = kg * KPB + g;

    const float4* __restrict__ cw = cws + (size_t)k * 31;        // s_load path
    const uint4*  __restrict__ ob = offs + (size_t)k * P_ * 4;
    float* __restrict__ outk = out + ((size_t)b * K_ + k) * P_;
    const char* sb = (const char*)simg;

    for (int s = 0; s < 7; ++s) {
        const int p = s * 128 + lane;
        if (p < P_) {
            const uint4 q0 = ob[(size_t)p * 4 + 0];
            const uint4 q1 = ob[(size_t)p * 4 + 1];
            const uint4 q2 = ob[(size_t)p * 4 + 2];
            const uint4 q3 = ob[(size_t)p * 4 + 3];
            const unsigned ua[8] = {q0.x, q0.y, q0.z, q0.w, q1.x, q1.y, q1.z, q1.w};
            const unsigned ub[8] = {q2.x, q2.y, q2.z, q2.w, q3.x, q3.y, q3.z, q3.w};
            float va[16], vb[16];
            #pragma unroll
            for (int j = 0; j < 8; ++j) {
                va[2*j    ] = *(const float*)(sb + ((ua[j] & 0xffffu) << 2));
                va[2*j + 1] = *(const float*)(sb + ((ua[j] >> 16)     << 2));
                vb[2*j    ] = *(const float*)(sb + ((ub[j] & 0xffffu) << 2));
                vb[2*j + 1] = *(const float*)(sb + ((ub[j] >> 16)     << 2));
            }
            float y[16];
            #pragma unroll
            for (int l = 0; l < 16; ++l) {
                const float4 c = cw[l];
                y[l] = fmaf(c.w, va[l] * vb[l], fmaf(c.z, vb[l], fmaf(c.y, va[l], c.x)));
            }
            #pragma unroll
            for (int l = 0; l < 8; ++l) {
                const float4 c = cw[16 + l];
                const float a = y[2*l], bb = y[2*l + 1];
                y[l] = fmaf(c.w, a * bb, fmaf(c.z, bb, fmaf(c.y, a, c.x)));
            }
            #pragma unroll
            for (int l = 0; l < 4; ++l) {
                const float4 c = cw[24 + l];
                const float a = y[2*l], bb = y[2*l + 1];
                y[l] = fmaf(c.w, a * bb, fmaf(c.z, bb, fmaf(c.y, a, c.x)));
            }
            #pragma unroll
            for (int l = 0; l < 2; ++l) {
                const float4 c = cw[28 + l];
                const float a = y[2*l], bb = y[2*l + 1];
                y[l] = fmaf(c.w, a * bb, fmaf(c.z, bb, fmaf(c.y, a, c.x)));
            }
            {
                const float4 c = cw[30];
                const float a = y[0], bb = y[1];
                outk[p] = fmaf(c.w, a * bb, fmaf(c.z, bb, fmaf(c.y, a, c.x)));
            }
        }
    }
}

extern "C" void kernel_launch(void* const* d_in, const int* in_sizes, int n_in,
                              void* d_out, int out_size, void* d_ws, size_t ws_size,
                              hipStream_t stream) {
    const float* x     = (const float*)d_in[0];
    const float* w0    = (const float*)d_in[1];
    const float* w1    = (const float*)d_in[2];
    const float* w2    = (const float*)d_in[3];
    const float* w3    = (const float*)d_in[4];
    const float* w4    = (const float*)d_in[5];
    const int*   a_idx = (const int*)d_in[6];
    const int*   b_idx = (const int*)d_in[7];
    float* out = (float*)d_out;

    uint4*  offs = (uint4*)d_ws;                                 // 3.2 MB
    float4* cws  = (float4*)((char*)d_ws + (size_t)SITES * 64);  // 31 KB

    pack_offsets<<<(SITES + 255) / 256, 256, 0, stream>>>(a_idx, b_idx, offs);
    coef_kernel<<<(K_ * 31 + 255) / 256, 256, 0, stream>>>(w0, w1, w2, w3, w4, cws);

    logicconv_main<<<B_ * NKG, 1024, 0, stream>>>(x, offs, cws, out);
}

// Round 6
// 40.015 us; speedup vs baseline: 16.2576x; 1.1887x over previous
//
#include <hip/hip_runtime.h>
#include <hip/hip_bf16.h>

// LogicConv3d: B=64, C=32, H=32, W=32, K=64, P=28*28=784, S=16 gathers/side.
// R6: R5's LDS-gather design (ds-pipe-bound, ~16us floor) with structural
// overhead removed:
//  - prep kernel fuses pack_offsets + coef (one launch fewer). Coefs stay in
//    GLOBAL memory so main reads them via wave-uniform s_load (SMEM pipe),
//    keeping the saturated LDS pipe free.
//  - main: KPB=16 -> 256 blocks = exactly 1/CU (LDS-capped anyway): ONE
//    staging round instead of two serial ones; offs L2 traffic halved.

#define B_  64
#define C_  32
#define H_  32
#define W_  32
#define K_  64
#define P_  784
#define CHW (C_*H_*W_)      // 32768 floats = 128 KB
#define HW  (H_*W_)         // 1024
#define SITES (K_*P_)       // 50176
#define KPB 16              // k's per block
#define NKG (K_/KPB)        // 4 kgroups
#define NPACKBLK ((SITES + 255) / 256)          // 196
#define NCOEFBLK ((K_ * 31 + 255) / 256)        // 8

__constant__ float COEF_[16][4] = {
    {0, 0, 0, 0}, {0, 0, 0, 1}, {0, 1, 0, -1}, {0, 1, 0, 0},
    {0, 0, 1, -1}, {0, 0, 1, 0}, {0, 1, 1, -2}, {0, 1, 1, -1},
    {1, -1, -1, 1}, {1, -1, -1, 2}, {1, 0, -1, 0}, {1, 0, -1, 1},
    {1, -1, 0, 0}, {1, -1, 0, 1}, {1, 0, 0, -1}, {1, 0, 0, 0}
};

// ---- kernel 1: fused prep = pack offsets (blocks 0..195) + coefs (196..203) ----
__global__ __launch_bounds__(256) void prep_kernel(
    const int* __restrict__ a_idx, const int* __restrict__ b_idx,
    const float* __restrict__ w0, const float* __restrict__ w1,
    const float* __restrict__ w2, const float* __restrict__ w3,
    const float* __restrict__ w4,
    uint4* __restrict__ offs,    // [SITES][4] uint4 = 32 u16 offsets
    float4* __restrict__ cws)    // [K_*31]
{
    const int bid = blockIdx.x;
    const int tid = threadIdx.x;

    if (bid < NPACKBLK) {
        const int site = bid * 256 + tid;
        if (site >= SITES) return;

        unsigned int pk[16];
        {
            int tmp[48];
            const int4* v = (const int4*)(a_idx + (size_t)site * 48);
            #pragma unroll
            for (int j = 0; j < 12; ++j) ((int4*)tmp)[j] = v[j];
            #pragma unroll
            for (int l = 0; l < 8; ++l) {
                unsigned int o0 = (unsigned)(tmp[(2*l  )*3+2]*HW + tmp[(2*l  )*3+0]*W_ + tmp[(2*l  )*3+1]);
                unsigned int o1 = (unsigned)(tmp[(2*l+1)*3+2]*HW + tmp[(2*l+1)*3+0]*W_ + tmp[(2*l+1)*3+1]);
                pk[l] = o0 | (o1 << 16);
            }
        }
        {
            int tmp[48];
            const int4* v = (const int4*)(b_idx + (size_t)site * 48);
            #pragma unroll
            for (int j = 0; j < 12; ++j) ((int4*)tmp)[j] = v[j];
            #pragma unroll
            for (int l = 0; l < 8; ++l) {
                unsigned int o0 = (unsigned)(tmp[(2*l  )*3+2]*HW + tmp[(2*l  )*3+0]*W_ + tmp[(2*l  )*3+1]);
                unsigned int o1 = (unsigned)(tmp[(2*l+1)*3+2]*HW + tmp[(2*l+1)*3+0]*W_ + tmp[(2*l+1)*3+1]);
                pk[8 + l] = o0 | (o1 << 16);
            }
        }
        uint4* dst = offs + (size_t)site * 4;
        dst[0] = make_uint4(pk[0],  pk[1],  pk[2],  pk[3]);
        dst[1] = make_uint4(pk[4],  pk[5],  pk[6],  pk[7]);
        dst[2] = make_uint4(pk[8],  pk[9],  pk[10], pk[11]);
        dst[3] = make_uint4(pk[12], pk[13], pk[14], pk[15]);
    } else {
        const int t = (bid - NPACKBLK) * 256 + tid;
        if (t >= K_ * 31) return;
        const int k = t / 31;
        const int node = t - k * 31;
        int d, l;
        if      (node < 16) { d = 0; l = node; }
        else if (node < 24) { d = 1; l = node - 16; }
        else if (node < 28) { d = 2; l = node - 24; }
        else if (node < 30) { d = 3; l = node - 28; }
        else                { d = 4; l = 0; }
        const float* W;
        switch (d) {
            case 0: W = w0; break;
            case 1: W = w1; break;
            case 2: W = w2; break;
            case 3: W = w3; break;
            default: W = w4; break;
        }
        const float* row = W + ((size_t)l * K_ + k) * 16;
        float m = row[0];
        #pragma unroll
        for (int o = 1; o < 16; ++o) m = fmaxf(m, row[o]);
        float e[16];
        float Z = 0.0f;
        #pragma unroll
        for (int o = 0; o < 16; ++o) { e[o] = expf(row[o] - m); Z += e[o]; }
        const float inv = 1.0f / Z;
        float c0 = 0.f, c1 = 0.f, c2 = 0.f, c3 = 0.f;
        #pragma unroll
        for (int o = 0; o < 16; ++o) {
            c0 += e[o] * COEF_[o][0];
            c1 += e[o] * COEF_[o][1];
            c2 += e[o] * COEF_[o][2];
            c3 += e[o] * COEF_[o][3];
        }
        cws[t] = make_float4(c0 * inv, c1 * inv, c2 * inv, c3 * inv);
    }
}

// ---- kernel 2: main (LDS-gather, 1 block/CU) ----
__global__ __launch_bounds__(1024) void logicconv_main(
    const float* __restrict__ x,
    const uint4* __restrict__ offs,
    const float4* __restrict__ cws,
    float* __restrict__ out)
{
    __shared__ float simg[CHW];   // 128 KB -> 1 block/CU

    const int tid = threadIdx.x;
    const int bid = blockIdx.x;
    const int b   = bid >> 2;     // image
    const int kg  = bid & 3;      // k-group of 16

    // ---- stage image b into LDS (coalesced float4) ----
    {
        const float4* xi = (const float4*)(x + (size_t)b * CHW);
        float4* si = (float4*)simg;
        #pragma unroll
        for (int j = 0; j < CHW / 4 / 1024; ++j)   // 8 iters
            si[tid + j * 1024] = xi[tid + j * 1024];
    }
    __syncthreads();

    // ---- 8 groups of 128 threads; each group owns 2 k's (wave-uniform) ----
    const int g    = __builtin_amdgcn_readfirstlane(tid >> 7);   // 0..7
    const int lane = tid & 127;
    const char* sb = (const char*)simg;

    #pragma unroll
    for (int kk = 0; kk < KPB / 8; ++kk) {        // 2 k's per group
        const int k = kg * KPB + kk * 8 + g;

        const float4* __restrict__ cw = cws + (size_t)k * 31;    // s_load path
        const uint4*  __restrict__ ob = offs + (size_t)k * P_ * 4;
        float* __restrict__ outk = out + ((size_t)b * K_ + k) * P_;

        for (int s = 0; s < 7; ++s) {
            const int p = s * 128 + lane;
            if (p < P_) {
                const uint4 q0 = ob[(size_t)p * 4 + 0];
                const uint4 q1 = ob[(size_t)p * 4 + 1];
                const uint4 q2 = ob[(size_t)p * 4 + 2];
                const uint4 q3 = ob[(size_t)p * 4 + 3];
                const unsigned ua[8] = {q0.x, q0.y, q0.z, q0.w, q1.x, q1.y, q1.z, q1.w};
                const unsigned ub[8] = {q2.x, q2.y, q2.z, q2.w, q3.x, q3.y, q3.z, q3.w};
                float va[16], vb[16];
                #pragma unroll
                for (int j = 0; j < 8; ++j) {
                    va[2*j    ] = *(const float*)(sb + ((ua[j] & 0xffffu) << 2));
                    va[2*j + 1] = *(const float*)(sb + ((ua[j] >> 16)     << 2));
                    vb[2*j    ] = *(const float*)(sb + ((ub[j] & 0xffffu) << 2));
                    vb[2*j + 1] = *(const float*)(sb + ((ub[j] >> 16)     << 2));
                }
                float y[16];
                #pragma unroll
                for (int l = 0; l < 16; ++l) {
                    const float4 c = cw[l];
                    y[l] = fmaf(c.w, va[l] * vb[l], fmaf(c.z, vb[l], fmaf(c.y, va[l], c.x)));
                }
                #pragma unroll
                for (int l = 0; l < 8; ++l) {
                    const float4 c = cw[16 + l];
                    const float a = y[2*l], bb = y[2*l + 1];
                    y[l] = fmaf(c.w, a * bb, fmaf(c.z, bb, fmaf(c.y, a, c.x)));
                }
                #pragma unroll
                for (int l = 0; l < 4; ++l) {
                    const float4 c = cw[24 + l];
                    const float a = y[2*l], bb = y[2*l + 1];
                    y[l] = fmaf(c.w, a * bb, fmaf(c.z, bb, fmaf(c.y, a, c.x)));
                }
                #pragma unroll
                for (int l = 0; l < 2; ++l) {
                    const float4 c = cw[28 + l];
                    const float a = y[2*l], bb = y[2*l + 1];
                    y[l] = fmaf(c.w, a * bb, fmaf(c.z, bb, fmaf(c.y, a, c.x)));
                }
                {
                    const float4 c = cw[30];
                    const float a = y[0], bb = y[1];
                    outk[p] = fmaf(c.w, a * bb, fmaf(c.z, bb, fmaf(c.y, a, c.x)));
                }
            }
        }
    }
}

extern "C" void kernel_launch(void* const* d_in, const int* in_sizes, int n_in,
                              void* d_out, int out_size, void* d_ws, size_t ws_size,
                              hipStream_t stream) {
    const float* x     = (const float*)d_in[0];
    const float* w0    = (const float*)d_in[1];
    const float* w1    = (const float*)d_in[2];
    const float* w2    = (const float*)d_in[3];
    const float* w3    = (const float*)d_in[4];
    const float* w4    = (const float*)d_in[5];
    const int*   a_idx = (const int*)d_in[6];
    const int*   b_idx = (const int*)d_in[7];
    float* out = (float*)d_out;

    uint4*  offs = (uint4*)d_ws;                                 // 3.2 MB
    float4* cws  = (float4*)((char*)d_ws + (size_t)SITES * 64);  // 31 KB

    prep_kernel<<<NPACKBLK + NCOEFBLK, 256, 0, stream>>>(
        a_idx, b_idx, w0, w1, w2, w3, w4, offs, cws);

    logicconv_main<<<B_ * NKG, 1024, 0, stream>>>(x, offs, cws, out);
}